// Round 2
// baseline (123.613 us; speedup 1.0000x reference)
//
#include <hip/hip_runtime.h>

#define BLOCK 256

// One thread per (b,n) atom, grid-stride, NO in-loop barriers.
// Output written directly as 7x float4 per thread (112B stride); the wave's
// 7 back-to-back stores fully cover a contiguous 7168B span -> L2 merges to
// full lines. atom/type tables in LDS (vector-gathered); W/b read uniformly
// (compiler keeps them in SGPRs / scalar cache).
__global__ __launch_bounds__(BLOCK, 6) void efp_kernel(
    const float* __restrict__ info,   // [M,7]
    const float* __restrict__ mask,   // [M]
    const float* __restrict__ W,      // [16,5]
    const float* __restrict__ bias,   // [16]
    const float* __restrict__ atom,   // [95,8]
    const float* __restrict__ typ,    // [6,4]
    float* __restrict__ out,          // [M,28]
    int ntiles)
{
    __shared__ float4 s_atom[95 * 2];   // row Z = 2 aligned float4s
    __shared__ float4 s_typ[6];

    const int tid = threadIdx.x;
    if (tid < 95 * 2) s_atom[tid] = reinterpret_cast<const float4*>(atom)[tid];
    if (tid < 6)      s_typ[tid]  = reinterpret_cast<const float4*>(typ)[tid];
    __syncthreads();   // once per block, before the loop

    for (int tile = blockIdx.x; tile < ntiles; tile += gridDim.x) {
        const long long i = (long long)tile * BLOCK + tid;

        const float m = mask[i];
        const float* gi = info + i * 7;
        float r[7];
        #pragma unroll
        for (int k = 0; k < 7; ++k) r[k] = gi[k];

        // exact reference semantics
        const float f0 = r[0] * m, f1 = r[1] * m, f2 = r[2] * m,
                    f3 = r[3] * m, f4 = r[4] * m;
        const int an = (int)(r[5] * m);     // trunc toward zero (.astype int)
        const int et = (int)(r[6] * m);
        const bool active = (m >= 0.5f);
        const bool valid  = active && (an >= 1) && (an <= 94);
        const int anc = min(max(an, 0), 94);
        const int etc = min(max(et, 0), 5);
        const float sc_ff  = active ? m : 0.0f;  // folds where(active)·mask
        const float sc_emb = valid  ? m : 0.0f;

        float4 o[7];
        float* of = reinterpret_cast<float*>(o);

        #pragma unroll
        for (int oo = 0; oo < 16; ++oo) {       // W/b uniform -> SGPRs
            float acc = bias[oo];
            acc = fmaf(W[oo * 5 + 0], f0, acc);
            acc = fmaf(W[oo * 5 + 1], f1, acc);
            acc = fmaf(W[oo * 5 + 2], f2, acc);
            acc = fmaf(W[oo * 5 + 3], f3, acc);
            acc = fmaf(W[oo * 5 + 4], f4, acc);
            of[oo] = fmaxf(acc, 0.0f) * sc_ff;
        }

        const float4 a0 = s_atom[anc * 2 + 0];  // ds_read_b128
        const float4 a1 = s_atom[anc * 2 + 1];
        const float4 t0 = s_typ[etc];
        o[4] = make_float4(a0.x * sc_emb, a0.y * sc_emb, a0.z * sc_emb, a0.w * sc_emb);
        o[5] = make_float4(a1.x * sc_emb, a1.y * sc_emb, a1.z * sc_emb, a1.w * sc_emb);
        o[6] = make_float4(t0.x * sc_emb, t0.y * sc_emb, t0.z * sc_emb, t0.w * sc_emb);

        float4* go = reinterpret_cast<float4*>(out + i * 28);  // 112B-aligned
        #pragma unroll
        for (int k = 0; k < 7; ++k) go[k] = o[k];
    }
}

extern "C" void kernel_launch(void* const* d_in, const int* in_sizes, int n_in,
                              void* d_out, int out_size, void* d_ws, size_t ws_size,
                              hipStream_t stream) {
    const float* info = (const float*)d_in[0];
    const float* mask = (const float*)d_in[1];
    const float* W    = (const float*)d_in[2];
    const float* bias = (const float*)d_in[3];
    const float* atom = (const float*)d_in[4];
    const float* typ  = (const float*)d_in[5];
    float* out = (float*)d_out;

    const int M = in_sizes[1];           // B*N, divisible by 256
    const int ntiles = M / BLOCK;
    int grid = ntiles < 2048 ? ntiles : 2048;

    hipLaunchKernelGGL(efp_kernel, dim3(grid), dim3(BLOCK), 0, stream,
                       info, mask, W, bias, atom, typ, out, ntiles);
}

// Round 3
// 63.046 us; speedup vs baseline: 1.9607x; 1.9607x over previous
//
#include <hip/hip_runtime.h>

#define BLOCK 256

// One thread per atom. Each WAVE owns a private [64][29] LDS staging region
// for its own 64 atoms and cooperatively stores its own contiguous 7KB output
// span as float4. No __syncthreads in the loop: all LDS communication is
// intra-wave (HW executes a wave's DS ops in order; compiler fenced with
// s_waitcnt lgkmcnt(0) + sched_barrier(0) per guide rule #18).
__global__ __launch_bounds__(BLOCK, 4) void efp_kernel(
    const float* __restrict__ info,   // [M,7]
    const float* __restrict__ mask,   // [M]
    const float* __restrict__ W,      // [16,5]  (uniform -> SGPR)
    const float* __restrict__ bias,   // [16]
    const float* __restrict__ atom,   // [95,8]
    const float* __restrict__ typ,    // [6,4]
    float* __restrict__ out,          // [M,28]
    int ntiles)
{
    __shared__ float4 s_atom[95 * 3];      // rows padded to 48B: 12a mod 32 -> 8 bank groups
    __shared__ float4 s_typ[6];
    __shared__ float  s_out[4][64 * 29];   // per-wave region; 29 coprime w/ 32 banks

    const int tid = threadIdx.x;
    const int wid = tid >> 6;
    const int lane = tid & 63;

    if (tid < 190) {                       // stage tables once
        const int a = tid >> 1, j = tid & 1;
        s_atom[a * 3 + j] = reinterpret_cast<const float4*>(atom)[tid];
    }
    if (tid < 6) s_typ[tid] = reinterpret_cast<const float4*>(typ)[tid];
    __syncthreads();                       // only barrier in the kernel

    float* const sw = s_out[wid];

    for (int tile = blockIdx.x; tile < ntiles; tile += gridDim.x) {
        const long long abase = (long long)tile * BLOCK + wid * 64;  // wave's 64 atoms
        const long long i = abase + lane;

        const float m = mask[i];
        const float* gi = info + i * 7;
        const float r0 = gi[0], r1 = gi[1], r2 = gi[2], r3 = gi[3],
                    r4 = gi[4], r5 = gi[5], r6 = gi[6];

        // exact reference semantics
        const float f0 = r0 * m, f1 = r1 * m, f2 = r2 * m, f3 = r3 * m, f4 = r4 * m;
        const int an = (int)(r5 * m);          // trunc toward zero (.astype int32)
        const int et = (int)(r6 * m);
        const bool active = (m >= 0.5f);
        const bool valid  = active && (an >= 1) && (an <= 94);
        const int anc = min(max(an, 0), 94);
        const int etc = min(max(et, 0), 5);
        const float sc_ff  = active ? m : 0.0f;   // folds where(active)·mask
        const float sc_emb = valid  ? m : 0.0f;

        float* so = sw + lane * 29;
        #pragma unroll
        for (int o = 0; o < 16; ++o) {            // W/b uniform -> scalar regs
            float acc = bias[o];
            acc = fmaf(W[o * 5 + 0], f0, acc);
            acc = fmaf(W[o * 5 + 1], f1, acc);
            acc = fmaf(W[o * 5 + 2], f2, acc);
            acc = fmaf(W[o * 5 + 3], f3, acc);
            acc = fmaf(W[o * 5 + 4], f4, acc);
            so[o] = fmaxf(acc, 0.0f) * sc_ff;
        }
        const float4 a0 = s_atom[anc * 3 + 0];
        const float4 a1 = s_atom[anc * 3 + 1];
        const float4 t0 = s_typ[etc];
        so[16] = a0.x * sc_emb;  so[17] = a0.y * sc_emb;
        so[18] = a0.z * sc_emb;  so[19] = a0.w * sc_emb;
        so[20] = a1.x * sc_emb;  so[21] = a1.y * sc_emb;
        so[22] = a1.z * sc_emb;  so[23] = a1.w * sc_emb;
        so[24] = t0.x * sc_emb;  so[25] = t0.y * sc_emb;
        so[26] = t0.z * sc_emb;  so[27] = t0.w * sc_emb;

        // intra-wave fence: all ds_writes visible before cross-lane ds_reads
        asm volatile("s_waitcnt lgkmcnt(0)" ::: "memory");
        __builtin_amdgcn_sched_barrier(0);

        // coop store of this wave's 64 atoms: 448 contiguous float4 (7168B)
        float4* go = reinterpret_cast<float4*>(out) + abase * 7;
        #pragma unroll
        for (int k = 0; k < 7; ++k) {
            const int l = k * 64 + lane;          // 0..447
            const int row = l / 7;                // magic-mul
            const int col = (l - row * 7) * 4;
            const float* sr = sw + row * 29 + col;
            go[l] = make_float4(sr[0], sr[1], sr[2], sr[3]);
        }

        // WAR fence: next tile's ds_writes must not be hoisted above this
        // tile's ds_reads (HW keeps a wave's DS ops in issue order).
        asm volatile("" ::: "memory");
        __builtin_amdgcn_sched_barrier(0);
    }
}

extern "C" void kernel_launch(void* const* d_in, const int* in_sizes, int n_in,
                              void* d_out, int out_size, void* d_ws, size_t ws_size,
                              hipStream_t stream) {
    const float* info = (const float*)d_in[0];
    const float* mask = (const float*)d_in[1];
    const float* W    = (const float*)d_in[2];
    const float* bias = (const float*)d_in[3];
    const float* atom = (const float*)d_in[4];
    const float* typ  = (const float*)d_in[5];
    float* out = (float*)d_out;

    const int M = in_sizes[1];           // B*N, divisible by 256
    const int ntiles = M / BLOCK;
    int grid = ntiles < 2048 ? ntiles : 2048;

    hipLaunchKernelGGL(efp_kernel, dim3(grid), dim3(BLOCK), 0, stream,
                       info, mask, W, bias, atom, typ, out, ntiles);
}